// Round 1
// baseline (16516.936 us; speedup 1.0000x reference)
//
#include <hip/hip_runtime.h>
#include <hip/hip_bf16.h>
#include <math.h>

#define B_ 128
#define S_ 1024
#define H_ 512
#define E_ 512
#define T_ 64
#define L_ 128
#define G4H 2048  // 4*H

__device__ inline float sigmoidf_(float x) { return 1.f / (1.f + expf(-x)); }
__device__ inline float fast_tanhf_(float x) {
    float e = __expf(2.f * x);
    return 1.f - 2.f / (e + 1.f);
}

// ---------------------------------------------------------------------------
// Generic fp32 GEMM:  C[m,n] = act( A[m,:]·W[n,:] + bias[n] + Cinit[m,n] )
// A [M,K] row-major (lda), W [N,K] row-major (ldw).  M,N multiples of 64,
// K multiple of 16.  Tile 64x64, 256 threads, 4x4 per thread.
// ---------------------------------------------------------------------------
__global__ __launch_bounds__(256) void gemm_nt(
    const float* __restrict__ A, int lda,
    const float* __restrict__ W, int ldw,
    const float* __restrict__ bias,
    const float* __restrict__ Cinit, int ldci,
    float* __restrict__ C, int ldc,
    int K, int act)
{
    __shared__ float As[16][64];
    __shared__ float Ws[16][64];
    const int m0 = blockIdx.x * 64;
    const int n0 = blockIdx.y * 64;
    const int t = threadIdx.x;
    const int tx = t & 15;        // n direction
    const int ty = t >> 4;        // m direction
    const int lr = t >> 2;        // 0..63 row of tile to load
    const int lk = (t & 3) * 4;   // k offset within 16

    float acc[4][4] = {};

    for (int k0 = 0; k0 < K; k0 += 16) {
        float4 a4 = *reinterpret_cast<const float4*>(A + (size_t)(m0 + lr) * lda + k0 + lk);
        float4 w4 = *reinterpret_cast<const float4*>(W + (size_t)(n0 + lr) * ldw + k0 + lk);
        As[lk + 0][lr] = a4.x; As[lk + 1][lr] = a4.y; As[lk + 2][lr] = a4.z; As[lk + 3][lr] = a4.w;
        Ws[lk + 0][lr] = w4.x; Ws[lk + 1][lr] = w4.y; Ws[lk + 2][lr] = w4.z; Ws[lk + 3][lr] = w4.w;
        __syncthreads();
#pragma unroll
        for (int kk = 0; kk < 16; ++kk) {
            float a[4], b[4];
#pragma unroll
            for (int i = 0; i < 4; ++i) a[i] = As[kk][ty * 4 + i];
#pragma unroll
            for (int j = 0; j < 4; ++j) b[j] = Ws[kk][tx * 4 + j];
#pragma unroll
            for (int i = 0; i < 4; ++i)
#pragma unroll
                for (int j = 0; j < 4; ++j) acc[i][j] = fmaf(a[i], b[j], acc[i][j]);
        }
        __syncthreads();
    }

#pragma unroll
    for (int i = 0; i < 4; ++i) {
        const int m = m0 + ty * 4 + i;
#pragma unroll
        for (int j = 0; j < 4; ++j) {
            const int n = n0 + tx * 4 + j;
            float v = acc[i][j];
            if (bias)  v += bias[n];
            if (Cinit) v += Cinit[(size_t)m * ldci + n];
            if (act == 1) v = tanhf(v);
            C[(size_t)m * ldc + n] = v;
        }
    }
}

// ---------------------------------------------------------------------------
// Build X[T,B,E]: X[0]=decoder_input, X[t>=1][b]=label_emb[cur_labels[b][t-1]]
// ---------------------------------------------------------------------------
__global__ void k_embed(const float* __restrict__ dec_in, const int* __restrict__ labels,
                        const float* __restrict__ emb, float* __restrict__ X)
{
    size_t total = (size_t)T_ * B_ * E_;
    for (size_t i = (size_t)blockIdx.x * blockDim.x + threadIdx.x; i < total;
         i += (size_t)gridDim.x * blockDim.x) {
        int e = (int)(i % E_);
        int b = (int)((i / E_) % B_);
        int t = (int)(i / ((size_t)E_ * B_));
        float v;
        if (t == 0) v = dec_in[b * E_ + e];
        else {
            int lab = labels[b * T_ + (t - 1)];
            v = emb[(size_t)lab * E_ + e];
        }
        X[i] = v;
    }
}

// init: cat3[:,0:512]=h0, cbuf=c0, bsum=b_ih+b_hh
__global__ void k_init(const float* __restrict__ h0, const float* __restrict__ c0,
                       const float* __restrict__ b_ih, const float* __restrict__ b_hh,
                       float* __restrict__ cat3, float* __restrict__ cbuf, float* __restrict__ bsum)
{
    int i = blockIdx.x * blockDim.x + threadIdx.x;   // 0 .. B*H-1
    int b = i / H_, h = i % H_;
    cat3[b * 1024 + h] = h0[i];
    cbuf[i] = c0[i];
    if (i < G4H) bsum[i] = b_ih[i] + b_hh[i];
}

// LSTM pointwise: gates[B,2048] (i,f,g,o), c update, h_lstm -> cat1[:,512:1024]
__global__ __launch_bounds__(256) void k_lstm(const float* __restrict__ gates,
                                              float* __restrict__ cbuf, float* __restrict__ cat1)
{
    int i = blockIdx.x * blockDim.x + threadIdx.x;   // B*H
    int b = i / H_, h = i % H_;
    const float* g = gates + (size_t)b * G4H;
    float ig = sigmoidf_(g[h]);
    float fg = sigmoidf_(g[h + 512]);
    float gg = tanhf(g[h + 1024]);
    float og = sigmoidf_(g[h + 1536]);
    float c = fg * cbuf[i] + ig * gg;
    cbuf[i] = c;
    cat1[b * 1024 + 512 + h] = og * tanhf(c);
}

// ---------------------------------------------------------------------------
// Attention: block (b, quarter) handles 256 s-values. 512 thr = 8 waves,
// each wave 32 s, online softmax; lane owns h = lane*8+k.
// Writes partial (m, l, w[512]) per block.
// ---------------------------------------------------------------------------
__global__ __launch_bounds__(512) void k_attn(const float* __restrict__ ctx,
    const float* __restrict__ inp, const float* __restrict__ Vv,
    float* __restrict__ pm, float* __restrict__ pl, float* __restrict__ pw)
{
    int blk = blockIdx.x;
    int b = blk >> 2, q = blk & 3;
    int tid = threadIdx.x, lane = tid & 63, wv = tid >> 6;

    float inpr[8], vr[8];
    {
        const float4* ip4 = reinterpret_cast<const float4*>(inp + (size_t)b * H_) + lane * 2;
        const float4* v4 = reinterpret_cast<const float4*>(Vv) + lane * 2;
        *(float4*)&inpr[0] = ip4[0]; *(float4*)&inpr[4] = ip4[1];
        *(float4*)&vr[0] = v4[0];   *(float4*)&vr[4] = v4[1];
    }
    const float* cbase = ctx + (size_t)b * S_ * H_ + (size_t)(q * 256) * H_;

    float m = -INFINITY, l = 0.f, w[8] = {};
    for (int si = 0; si < 32; ++si) {
        int s = wv * 32 + si;
        const float4* cp = reinterpret_cast<const float4*>(cbase + (size_t)s * H_) + lane * 2;
        float c8[8];
        *(float4*)&c8[0] = cp[0]; *(float4*)&c8[4] = cp[1];
        float t = 0.f;
#pragma unroll
        for (int k = 0; k < 8; ++k) t = fmaf(fast_tanhf_(inpr[k] + c8[k]), vr[k], t);
#pragma unroll
        for (int off = 32; off > 0; off >>= 1) t += __shfl_xor(t, off);
        float mn = fmaxf(m, t);
        float sc = __expf(m - mn);
        float p  = __expf(t - mn);
        l = l * sc + p;
#pragma unroll
        for (int k = 0; k < 8; ++k) w[k] = w[k] * sc + p * c8[k];
        m = mn;
    }

    __shared__ float wl[8 * 512];
    __shared__ float ml[8], ll[8];
#pragma unroll
    for (int k = 0; k < 8; ++k) wl[wv * 512 + lane * 8 + k] = w[k];
    if (lane == 0) { ml[wv] = m; ll[wv] = l; }
    __syncthreads();

    float M = ml[0];
#pragma unroll
    for (int u = 1; u < 8; ++u) M = fmaxf(M, ml[u]);
    float lt = 0.f, wt = 0.f;
#pragma unroll
    for (int u = 0; u < 8; ++u) {
        float e = __expf(ml[u] - M);
        lt += e * ll[u];
        wt += e * wl[u * 512 + tid];
    }
    if (tid == 0) { pm[blk] = M; pl[blk] = lt; }
    pw[(size_t)blk * 512 + tid] = wt;
}

// merge 4 quarter-partials -> weighted; write to cat1[:,0:512] and cat3[:,512:1024]
__global__ __launch_bounds__(512) void k_merge(const float* __restrict__ pm,
    const float* __restrict__ pl, const float* __restrict__ pw,
    float* __restrict__ cat1, float* __restrict__ cat3)
{
    int b = blockIdx.x, h = threadIdx.x;
    float M = -INFINITY;
#pragma unroll
    for (int q = 0; q < 4; ++q) M = fmaxf(M, pm[4 * b + q]);
    float L = 0.f, wt = 0.f;
#pragma unroll
    for (int q = 0; q < 4; ++q) {
        float e = __expf(pm[4 * b + q] - M);
        L += e * pl[4 * b + q];
        wt += e * pw[(size_t)(4 * b + q) * 512 + h];
    }
    float wv = wt / L;
    cat1[b * 1024 + h] = wv;
    cat3[b * 1024 + 512 + h] = wv;
}

// argmax over L=128 logits per (b,t) row; first-index tie-break; store as float
__global__ __launch_bounds__(128) void k_argmax(const float* __restrict__ outp,
                                                float* __restrict__ preds)
{
    int row = blockIdx.x;             // b*T + t
    int tid = threadIdx.x;
    float v = outp[(size_t)row * L_ + tid];
    int idx = tid;
#pragma unroll
    for (int off = 32; off > 0; off >>= 1) {
        float ov = __shfl_xor(v, off);
        int oi = __shfl_xor(idx, off);
        if (ov > v || (ov == v && oi < idx)) { v = ov; idx = oi; }
    }
    __shared__ float sv[2];
    __shared__ int si[2];
    if ((tid & 63) == 0) { sv[tid >> 6] = v; si[tid >> 6] = idx; }
    __syncthreads();
    if (tid == 0) {
        float v0 = sv[0], v1 = sv[1];
        int i0 = si[0], i1 = si[1];
        int r = (v1 > v0 || (v1 == v0 && i1 < i0)) ? i1 : i0;
        preds[row] = (float)r;
    }
}

__global__ void k_final(const float* __restrict__ cat3, const float* __restrict__ cbuf,
                        float* __restrict__ hf, float* __restrict__ cf)
{
    int i = blockIdx.x * blockDim.x + threadIdx.x;   // B*H
    int b = i / H_, h = i % H_;
    hf[i] = cat3[b * 1024 + h];
    cf[i] = cbuf[i];
}

// ---------------------------------------------------------------------------
extern "C" void kernel_launch(void* const* d_in, const int* in_sizes, int n_in,
                              void* d_out, int out_size, void* d_ws, size_t ws_size,
                              hipStream_t stream)
{
    const float* dec_in  = (const float*)d_in[2];
    const float* h0      = (const float*)d_in[3];
    const float* c0      = (const float*)d_in[4];
    const float* context = (const float*)d_in[5];
    const int*   labels  = (const int*)d_in[6];
    const float* emb     = (const float*)d_in[8];
    const float* W_ih    = (const float*)d_in[9];
    const float* b_ih    = (const float*)d_in[10];
    const float* W_hh    = (const float*)d_in[11];
    const float* b_hh    = (const float*)d_in[12];
    const float* W_ho    = (const float*)d_in[13];
    const float* b_ho    = (const float*)d_in[14];
    const float* W_ain   = (const float*)d_in[15];
    const float* b_ain   = (const float*)d_in[16];
    const float* W_actx  = (const float*)d_in[17];
    const float* b_actx  = (const float*)d_in[18];
    const float* Vv      = (const float*)d_in[19];
    const float* W_out   = (const float*)d_in[20];
    const float* b_out   = (const float*)d_in[21];

    float* ws = (float*)d_ws;
    float* X     = ws; ws += (size_t)T_ * B_ * E_;      // 4.19M
    float* xproj = ws; ws += (size_t)T_ * B_ * G4H;     // 16.8M
    float* xout  = ws; ws += (size_t)T_ * B_ * L_;      // 1.05M
    float* ctx   = ws; ws += (size_t)B_ * S_ * H_;      // 67.1M
    float* gates = ws; ws += (size_t)B_ * G4H;
    float* cbuf  = ws; ws += (size_t)B_ * H_;
    float* cat1  = ws; ws += (size_t)B_ * 1024;         // [weighted | h_lstm]
    float* cat3  = ws; ws += (size_t)B_ * 1024;         // [hidden_t | weighted]
    float* inpb  = ws; ws += (size_t)B_ * H_;
    float* pm    = ws; ws += 512;
    float* pl    = ws; ws += 512;
    float* pw    = ws; ws += (size_t)512 * 512;
    float* bsum  = ws; ws += G4H;

    float* out_logits = (float*)d_out;
    float* out_preds  = out_logits + (size_t)B_ * T_ * L_;
    float* out_hf     = out_preds + (size_t)B_ * T_;
    float* out_cf     = out_hf + (size_t)B_ * H_;

    // ---- precompute ----
    k_embed<<<2048, 256, 0, stream>>>(dec_in, labels, emb, X);
    k_init<<<256, 256, 0, stream>>>(h0, c0, b_ih, b_hh, cat3, cbuf, bsum);
    // xproj[T*B,2048] = X @ W_ih^T + (b_ih+b_hh)
    gemm_nt<<<dim3(128, 32), 256, 0, stream>>>(X, E_, W_ih, E_, bsum, nullptr, 0,
                                               xproj, G4H, E_, 0);
    // xout[T*B,128] = X @ W_out[:,1024:1536]^T + b_out
    gemm_nt<<<dim3(128, 2), 256, 0, stream>>>(X, E_, W_out + 1024, 1536, b_out, nullptr, 0,
                                              xout, L_, E_, 0);
    // ctx[B*S,512] = context @ W_attn_ctx^T + b_attn_ctx
    gemm_nt<<<dim3(2048, 8), 256, 0, stream>>>(context, H_, W_actx, H_, b_actx, nullptr, 0,
                                               ctx, H_, H_, 0);

    // ---- sequential decode ----
    for (int t = 0; t < T_; ++t) {
        // gates = h @ W_hh^T + xproj[t]   (h = cat3[:,0:512])
        gemm_nt<<<dim3(2, 32), 256, 0, stream>>>(cat3, 1024, W_hh, H_, nullptr,
                                                 xproj + (size_t)t * B_ * G4H, G4H,
                                                 gates, G4H, H_, 0);
        k_lstm<<<256, 256, 0, stream>>>(gates, cbuf, cat1);
        // inp = h_lstm @ W_attn_in^T + b_attn_in
        gemm_nt<<<dim3(2, 8), 256, 0, stream>>>(cat1 + 512, 1024, W_ain, H_, b_ain,
                                                nullptr, 0, inpb, H_, H_, 0);
        k_attn<<<512, 512, 0, stream>>>(ctx, inpb, Vv, pm, pl, pw);
        k_merge<<<128, 512, 0, stream>>>(pm, pl, pw, cat1, cat3);
        // hidden_t = tanh([weighted,h_lstm] @ W_ho^T + b_ho)  -> cat3[:,0:512]
        gemm_nt<<<dim3(2, 8), 256, 0, stream>>>(cat1, 1024, W_ho, 1024, b_ho,
                                                nullptr, 0, cat3, 1024, 1024, 1);
        // logits = [hidden_t,weighted] @ W_out[:,0:1024]^T + xout[t]
        gemm_nt<<<dim3(2, 2), 256, 0, stream>>>(cat3, 1024, W_out, 1536, nullptr,
                                                xout + (size_t)t * B_ * L_, L_,
                                                out_logits + (size_t)t * L_, T_ * L_, 1024, 0);
    }

    k_argmax<<<B_ * T_, 128, 0, stream>>>(out_logits, out_preds);
    k_final<<<256, 256, 0, stream>>>(cat3, cbuf, out_hf, out_cf);
}

// Round 2
// 8915.629 us; speedup vs baseline: 1.8526x; 1.8526x over previous
//
#include <hip/hip_runtime.h>
#include <hip/hip_bf16.h>
#include <math.h>

#define B_ 128
#define S_ 1024
#define H_ 512
#define E_ 512
#define T_ 64
#define L_ 128
#define G4H 2048  // 4*H

__device__ inline float sigmoidf_(float x) { return 1.f / (1.f + expf(-x)); }
__device__ inline float fast_tanhf_(float x) {
    float e = __expf(2.f * x);
    return 1.f - 2.f / (e + 1.f);
}

// ---------------------------------------------------------------------------
// Big fp32 GEMM: tile 128x128, 256 thr, 8x8/thread.
// C[m,n] = act( A[m,:]·W[n,:] + bias[n] + Cinit[m,n] )
// M,N multiples of 128, K multiple of 16.
// perm==1: output row m=(t*B+b) is written to C[(b*T_+t)*ldc + n].
// ---------------------------------------------------------------------------
__global__ __launch_bounds__(256) void gemm128(
    const float* __restrict__ A, int lda,
    const float* __restrict__ W, int ldw,
    const float* __restrict__ bias,
    const float* __restrict__ Cinit, int ldci,
    float* __restrict__ C, int ldc,
    int K, int act, int perm)
{
    __shared__ float As[16][128];
    __shared__ float Ws[16][128];
    const int m0 = blockIdx.x * 128;
    const int n0 = blockIdx.y * 128;
    const int t = threadIdx.x;
    const int tx = t & 15;        // n: 8 cols
    const int ty = t >> 4;        // m: 8 rows
    const int lr = t >> 1;        // 0..127 row to load
    const int lk = (t & 1) * 8;   // k offset (two float4)

    float acc[8][8] = {};

    for (int k0 = 0; k0 < K; k0 += 16) {
        float4 a0 = *reinterpret_cast<const float4*>(A + (size_t)(m0 + lr) * lda + k0 + lk);
        float4 a1 = *reinterpret_cast<const float4*>(A + (size_t)(m0 + lr) * lda + k0 + lk + 4);
        float4 w0 = *reinterpret_cast<const float4*>(W + (size_t)(n0 + lr) * ldw + k0 + lk);
        float4 w1 = *reinterpret_cast<const float4*>(W + (size_t)(n0 + lr) * ldw + k0 + lk + 4);
        As[lk + 0][lr] = a0.x; As[lk + 1][lr] = a0.y; As[lk + 2][lr] = a0.z; As[lk + 3][lr] = a0.w;
        As[lk + 4][lr] = a1.x; As[lk + 5][lr] = a1.y; As[lk + 6][lr] = a1.z; As[lk + 7][lr] = a1.w;
        Ws[lk + 0][lr] = w0.x; Ws[lk + 1][lr] = w0.y; Ws[lk + 2][lr] = w0.z; Ws[lk + 3][lr] = w0.w;
        Ws[lk + 4][lr] = w1.x; Ws[lk + 5][lr] = w1.y; Ws[lk + 6][lr] = w1.z; Ws[lk + 7][lr] = w1.w;
        __syncthreads();
#pragma unroll
        for (int kk = 0; kk < 16; ++kk) {
            float a[8], b[8];
#pragma unroll
            for (int i = 0; i < 8; ++i) a[i] = As[kk][ty * 8 + i];
#pragma unroll
            for (int j = 0; j < 8; ++j) b[j] = Ws[kk][tx * 8 + j];
#pragma unroll
            for (int i = 0; i < 8; ++i)
#pragma unroll
                for (int j = 0; j < 8; ++j) acc[i][j] = fmaf(a[i], b[j], acc[i][j]);
        }
        __syncthreads();
    }

#pragma unroll
    for (int i = 0; i < 8; ++i) {
        const int m = m0 + ty * 8 + i;
        size_t crow;
        if (perm) { int bb = m & 127, tt = m >> 7; crow = ((size_t)bb * T_ + tt) * ldc; }
        else crow = (size_t)m * ldc;
#pragma unroll
        for (int j = 0; j < 8; ++j) {
            const int n = n0 + tx * 8 + j;
            float v = acc[i][j];
            if (bias)  v += bias[n];
            if (Cinit) v += Cinit[(size_t)m * ldci + n];
            if (act == 1) v = tanhf(v);
            C[crow + n] = v;
        }
    }
}

// ---------------------------------------------------------------------------
// Small-M GEMM with split-K: M=128 fixed, tile 128x64, K-chunk per blockIdx.y.
// Writes partials P[(ks*128 + m)*N + n]  (no bias, no act).
// ---------------------------------------------------------------------------
__global__ __launch_bounds__(256) void gemm_stepk(
    const float* __restrict__ A, int lda,
    const float* __restrict__ W, int ldw,
    float* __restrict__ P, int N, int Kc)
{
    __shared__ float As[16][128];
    __shared__ float Ws[16][64];
    const int n0 = blockIdx.x * 64;
    const int k0 = blockIdx.y * Kc;
    const int t = threadIdx.x;
    const int tx = t & 15;        // n: 4 cols
    const int ty = t >> 4;        // m: 8 rows
    const int ar = t >> 1, akq = (t & 1) * 8;
    const int wr = t >> 2, wkq = (t & 3) * 4;

    float acc[8][4] = {};

    for (int kb = 0; kb < Kc; kb += 16) {
        float4 a0 = *reinterpret_cast<const float4*>(A + (size_t)ar * lda + k0 + kb + akq);
        float4 a1 = *reinterpret_cast<const float4*>(A + (size_t)ar * lda + k0 + kb + akq + 4);
        float4 w0 = *reinterpret_cast<const float4*>(W + (size_t)(n0 + wr) * ldw + k0 + kb + wkq);
        As[akq + 0][ar] = a0.x; As[akq + 1][ar] = a0.y; As[akq + 2][ar] = a0.z; As[akq + 3][ar] = a0.w;
        As[akq + 4][ar] = a1.x; As[akq + 5][ar] = a1.y; As[akq + 6][ar] = a1.z; As[akq + 7][ar] = a1.w;
        Ws[wkq + 0][wr] = w0.x; Ws[wkq + 1][wr] = w0.y; Ws[wkq + 2][wr] = w0.z; Ws[wkq + 3][wr] = w0.w;
        __syncthreads();
#pragma unroll
        for (int kk = 0; kk < 16; ++kk) {
            float a[8], b[4];
#pragma unroll
            for (int i = 0; i < 8; ++i) a[i] = As[kk][ty * 8 + i];
#pragma unroll
            for (int j = 0; j < 4; ++j) b[j] = Ws[kk][tx * 4 + j];
#pragma unroll
            for (int i = 0; i < 8; ++i)
#pragma unroll
                for (int j = 0; j < 4; ++j) acc[i][j] = fmaf(a[i], b[j], acc[i][j]);
        }
        __syncthreads();
    }

#pragma unroll
    for (int i = 0; i < 8; ++i) {
        const int m = ty * 8 + i;
#pragma unroll
        for (int j = 0; j < 4; ++j)
            P[((size_t)blockIdx.y * 128 + m) * N + n0 + tx * 4 + j] = acc[i][j];
    }
}

// ---------------------------------------------------------------------------
__global__ void k_embed(const float* __restrict__ dec_in, const int* __restrict__ labels,
                        const float* __restrict__ emb, float* __restrict__ X)
{
    size_t total = (size_t)T_ * B_ * E_;
    for (size_t i = (size_t)blockIdx.x * blockDim.x + threadIdx.x; i < total;
         i += (size_t)gridDim.x * blockDim.x) {
        int e = (int)(i % E_);
        int b = (int)((i / E_) % B_);
        int t = (int)(i / ((size_t)E_ * B_));
        float v;
        if (t == 0) v = dec_in[b * E_ + e];
        else {
            int lab = labels[b * T_ + (t - 1)];
            v = emb[(size_t)lab * E_ + e];
        }
        X[i] = v;
    }
}

__global__ void k_init(const float* __restrict__ h0, const float* __restrict__ c0,
                       const float* __restrict__ b_ih, const float* __restrict__ b_hh,
                       float* __restrict__ hbuf, float* __restrict__ cbuf, float* __restrict__ bsum)
{
    int i = blockIdx.x * blockDim.x + threadIdx.x;   // 0 .. B*H-1
    hbuf[i] = h0[i];
    cbuf[i] = c0[i];
    if (i < G4H) bsum[i] = b_ih[i] + b_hh[i];
}

// LSTM pointwise from gate partials: gates = Pg0+Pg1+xproj[t]
__global__ __launch_bounds__(256) void k_lstm(const float* __restrict__ Pg,
                                              const float* __restrict__ xproj_t,
                                              float* __restrict__ cbuf, float* __restrict__ cat1)
{
    int i = blockIdx.x * blockDim.x + threadIdx.x;   // B*H
    int b = i >> 9, h = i & 511;
    const float* p0 = Pg + (size_t)b * G4H;
    const float* p1 = Pg + (size_t)(128 + b) * G4H;
    const float* xp = xproj_t + (size_t)b * G4H;
    float ig = sigmoidf_(p0[h] + p1[h] + xp[h]);
    float fg = sigmoidf_(p0[h + 512] + p1[h + 512] + xp[h + 512]);
    float gg = tanhf(p0[h + 1024] + p1[h + 1024] + xp[h + 1024]);
    float og = sigmoidf_(p0[h + 1536] + p1[h + 1536] + xp[h + 1536]);
    float c = fg * cbuf[i] + ig * gg;
    cbuf[i] = c;
    cat1[b * 1024 + 512 + h] = og * tanhf(c);
}

// ---------------------------------------------------------------------------
// Attention: block (b, quarter) handles 256 s-values. Prologue sums the 4
// W_attn_in split-K partials into inp (LDS). Writes partial (m,l,w[512]).
// ---------------------------------------------------------------------------
__global__ __launch_bounds__(512) void k_attn(const float* __restrict__ ctx,
    const float* __restrict__ Pa, const float* __restrict__ b_ain,
    const float* __restrict__ Vv,
    float* __restrict__ pm, float* __restrict__ pl, float* __restrict__ pw)
{
    int blk = blockIdx.x;
    int b = blk >> 2, q = blk & 3;
    int tid = threadIdx.x, lane = tid & 63, wv = tid >> 6;

    __shared__ float inp_sh[512];
    inp_sh[tid] = Pa[(size_t)b * 512 + tid]
                + Pa[(size_t)(128 + b) * 512 + tid]
                + Pa[(size_t)(256 + b) * 512 + tid]
                + Pa[(size_t)(384 + b) * 512 + tid]
                + b_ain[tid];
    __syncthreads();

    float inpr[8], vr[8];
    {
        const float4* v4 = reinterpret_cast<const float4*>(Vv) + lane * 2;
        *(float4*)&vr[0] = v4[0];   *(float4*)&vr[4] = v4[1];
#pragma unroll
        for (int k = 0; k < 8; ++k) inpr[k] = inp_sh[lane * 8 + k];
    }
    const float* cbase = ctx + (size_t)b * S_ * H_ + (size_t)(q * 256) * H_;

    float m = -INFINITY, l = 0.f, w[8] = {};
    for (int si = 0; si < 32; ++si) {
        int s = wv * 32 + si;
        const float4* cp = reinterpret_cast<const float4*>(cbase + (size_t)s * H_) + lane * 2;
        float c8[8];
        *(float4*)&c8[0] = cp[0]; *(float4*)&c8[4] = cp[1];
        float t = 0.f;
#pragma unroll
        for (int k = 0; k < 8; ++k) t = fmaf(fast_tanhf_(inpr[k] + c8[k]), vr[k], t);
#pragma unroll
        for (int off = 32; off > 0; off >>= 1) t += __shfl_xor(t, off);
        float mn = fmaxf(m, t);
        float sc = __expf(m - mn);
        float p  = __expf(t - mn);
        l = l * sc + p;
#pragma unroll
        for (int k = 0; k < 8; ++k) w[k] = w[k] * sc + p * c8[k];
        m = mn;
    }

    __shared__ float wl[8 * 512];
    __shared__ float ml[8], ll[8];
#pragma unroll
    for (int k = 0; k < 8; ++k) wl[wv * 512 + lane * 8 + k] = w[k];
    if (lane == 0) { ml[wv] = m; ll[wv] = l; }
    __syncthreads();

    float M = ml[0];
#pragma unroll
    for (int u = 1; u < 8; ++u) M = fmaxf(M, ml[u]);
    float lt = 0.f, wt = 0.f;
#pragma unroll
    for (int u = 0; u < 8; ++u) {
        float e = __expf(ml[u] - M);
        lt += e * ll[u];
        wt += e * wl[u * 512 + tid];
    }
    if (tid == 0) { pm[blk] = M; pl[blk] = lt; }
    pw[(size_t)blk * 512 + tid] = wt;
}

// merge 4 quarter-partials -> weighted; write cat1[:,0:512] and hist[t][:,512:1024]
__global__ __launch_bounds__(512) void k_merge(const float* __restrict__ pm,
    const float* __restrict__ pl, const float* __restrict__ pw,
    float* __restrict__ cat1, float* __restrict__ hist_t)
{
    int b = blockIdx.x, h = threadIdx.x;
    float M = -INFINITY;
#pragma unroll
    for (int q = 0; q < 4; ++q) M = fmaxf(M, pm[4 * b + q]);
    float L = 0.f, wt = 0.f;
#pragma unroll
    for (int q = 0; q < 4; ++q) {
        float e = __expf(pm[4 * b + q] - M);
        L += e * pl[4 * b + q];
        wt += e * pw[(size_t)(4 * b + q) * 512 + h];
    }
    float wv = wt / L;
    cat1[b * 1024 + h] = wv;
    hist_t[(size_t)b * 1024 + 512 + h] = wv;
}

// finalize W_ho: sum 8 partials + bias, tanh -> hbuf and hist[t][:,0:512]
__global__ __launch_bounds__(256) void k_whofin(const float* __restrict__ Po,
    const float* __restrict__ b_ho, float* __restrict__ hbuf, float* __restrict__ hist_t)
{
    int i = blockIdx.x * blockDim.x + threadIdx.x;   // B*H
    int b = i >> 9, h = i & 511;
    float v = b_ho[h];
#pragma unroll
    for (int ks = 0; ks < 8; ++ks) v += Po[((size_t)ks * 128 + b) * 512 + h];
    v = tanhf(v);
    hbuf[i] = v;
    hist_t[(size_t)b * 1024 + h] = v;
}

// argmax over L=128 logits per (b,t) row; first-index tie-break; store as float
__global__ __launch_bounds__(128) void k_argmax(const float* __restrict__ outp,
                                                float* __restrict__ preds)
{
    int row = blockIdx.x;             // b*T + t
    int tid = threadIdx.x;
    float v = outp[(size_t)row * L_ + tid];
    int idx = tid;
#pragma unroll
    for (int off = 32; off > 0; off >>= 1) {
        float ov = __shfl_xor(v, off);
        int oi = __shfl_xor(idx, off);
        if (ov > v || (ov == v && oi < idx)) { v = ov; idx = oi; }
    }
    __shared__ float sv[2];
    __shared__ int si[2];
    if ((tid & 63) == 0) { sv[tid >> 6] = v; si[tid >> 6] = idx; }
    __syncthreads();
    if (tid == 0) {
        float v0 = sv[0], v1 = sv[1];
        int i0 = si[0], i1 = si[1];
        int r = (v1 > v0 || (v1 == v0 && i1 < i0)) ? i1 : i0;
        preds[row] = (float)r;
    }
}

__global__ void k_final(const float* __restrict__ hbuf, const float* __restrict__ cbuf,
                        float* __restrict__ hf, float* __restrict__ cf)
{
    int i = blockIdx.x * blockDim.x + threadIdx.x;   // B*H
    hf[i] = hbuf[i];
    cf[i] = cbuf[i];
}

// ---------------------------------------------------------------------------
extern "C" void kernel_launch(void* const* d_in, const int* in_sizes, int n_in,
                              void* d_out, int out_size, void* d_ws, size_t ws_size,
                              hipStream_t stream)
{
    const float* dec_in  = (const float*)d_in[2];
    const float* h0      = (const float*)d_in[3];
    const float* c0      = (const float*)d_in[4];
    const float* context = (const float*)d_in[5];
    const int*   labels  = (const int*)d_in[6];
    const float* emb     = (const float*)d_in[8];
    const float* W_ih    = (const float*)d_in[9];
    const float* b_ih    = (const float*)d_in[10];
    const float* W_hh    = (const float*)d_in[11];
    const float* b_hh    = (const float*)d_in[12];
    const float* W_ho    = (const float*)d_in[13];
    const float* b_ho    = (const float*)d_in[14];
    const float* W_ain   = (const float*)d_in[15];
    const float* b_ain   = (const float*)d_in[16];
    const float* W_actx  = (const float*)d_in[17];
    const float* b_actx  = (const float*)d_in[18];
    const float* Vv      = (const float*)d_in[19];
    const float* W_out   = (const float*)d_in[20];
    const float* b_out   = (const float*)d_in[21];

    float* ws = (float*)d_ws;
    float* X     = ws; ws += (size_t)T_ * B_ * E_;      // 4.19M
    float* xproj = ws; ws += (size_t)T_ * B_ * G4H;     // 16.8M
    float* xout  = ws; ws += (size_t)T_ * B_ * L_;      // 1.05M  (t-major)
    float* ctx   = ws; ws += (size_t)B_ * S_ * H_;      // 67.1M
    float* hist  = ws; ws += (size_t)T_ * B_ * 1024;    // 8.39M  [hidden|weighted]
    float* Pg    = ws; ws += (size_t)2 * B_ * G4H;      // gates partials
    float* Pa    = ws; ws += (size_t)4 * B_ * H_;       // attn-in partials
    float* Po    = ws; ws += (size_t)8 * B_ * H_;       // W_ho partials
    float* cbuf  = ws; ws += (size_t)B_ * H_;
    float* cat1  = ws; ws += (size_t)B_ * 1024;         // [weighted | h_lstm]
    float* hbuf  = ws; ws += (size_t)B_ * H_;
    float* pm    = ws; ws += 512;
    float* pl    = ws; ws += 512;
    float* pw    = ws; ws += (size_t)512 * 512;
    float* bsum  = ws; ws += G4H;

    float* out_logits = (float*)d_out;                  // [B,T,L]
    float* out_preds  = out_logits + (size_t)B_ * T_ * L_;
    float* out_hf     = out_preds + (size_t)B_ * T_;
    float* out_cf     = out_hf + (size_t)B_ * H_;

    // ---- precompute ----
    k_embed<<<2048, 256, 0, stream>>>(dec_in, labels, emb, X);
    k_init<<<256, 256, 0, stream>>>(h0, c0, b_ih, b_hh, hbuf, cbuf, bsum);
    // xproj[T*B,2048] = X @ W_ih^T + (b_ih+b_hh)
    gemm128<<<dim3(64, 16), 256, 0, stream>>>(X, E_, W_ih, E_, bsum, nullptr, 0,
                                              xproj, G4H, E_, 0, 0);
    // xout[T*B,128] = X @ W_out[:,1024:1536]^T + b_out   (t-major)
    gemm128<<<dim3(64, 1), 256, 0, stream>>>(X, E_, W_out + 1024, 1536, b_out, nullptr, 0,
                                             xout, L_, E_, 0, 0);
    // ctx[B*S,512] = context @ W_attn_ctx^T + b_attn_ctx
    gemm128<<<dim3(1024, 4), 256, 0, stream>>>(context, H_, W_actx, H_, b_actx, nullptr, 0,
                                               ctx, H_, H_, 0, 0);

    // ---- sequential decode ----
    for (int t = 0; t < T_; ++t) {
        float* hist_t = hist + (size_t)t * B_ * 1024;
        // gate partials: h @ W_hh^T  (split-K 2x256)
        gemm_stepk<<<dim3(32, 2), 256, 0, stream>>>(hbuf, H_, W_hh, H_, Pg, G4H, 256);
        k_lstm<<<256, 256, 0, stream>>>(Pg, xproj + (size_t)t * B_ * G4H, cbuf, cat1);
        // attn-in partials: h_lstm @ W_attn_in^T  (split-K 4x128)
        gemm_stepk<<<dim3(8, 4), 256, 0, stream>>>(cat1 + 512, 1024, W_ain, H_, Pa, H_, 128);
        k_attn<<<512, 512, 0, stream>>>(ctx, Pa, b_ain, Vv, pm, pl, pw);
        k_merge<<<128, 512, 0, stream>>>(pm, pl, pw, cat1, hist_t);
        // W_ho partials: [weighted,h_lstm] @ W_ho^T  (split-K 8x128)
        gemm_stepk<<<dim3(8, 8), 256, 0, stream>>>(cat1, 1024, W_ho, 1024, Po, H_, 128);
        k_whofin<<<256, 256, 0, stream>>>(Po, b_ho, hbuf, hist_t);
    }

    // ---- deferred logits GEMM + argmax ----
    // logits[(b,t)] = hist[(t,b)] @ W_out[:,0:1024]^T + xout[(t,b)]
    gemm128<<<dim3(64, 1), 256, 0, stream>>>(hist, 1024, W_out, 1536, nullptr,
                                             xout, L_, out_logits, L_, 1024, 0, 1);
    k_argmax<<<B_ * T_, 128, 0, stream>>>(out_logits, out_preds);
    k_final<<<256, 256, 0, stream>>>(hbuf, cbuf, out_hf, out_cf);
}